// Round 18
// baseline (898.005 us; speedup 1.0000x reference)
//
#include <hip/hip_runtime.h>
#include <hip/hip_bf16.h>
#include <hip/hip_cooperative_groups.h>
namespace cg = cooperative_groups;

static constexpr int NN      = 50000;
static constexpr int FIN     = 1433;
static constexpr int KPAD    = 1440;            // 45 * 32
static constexpr int NB_SCAN = (NN + 255) / 256; // 196
static constexpr int L1B     = NN / 4;           // 12500 blocks, 1 node/wave
static constexpr int CSRG    = 1024;             // coop grid (4 blocks/CU, co-resident)

typedef __bf16 bf16x8 __attribute__((ext_vector_type(8)));
typedef float  f32x4  __attribute__((ext_vector_type(4)));

__device__ __forceinline__ float leaky02(float v){ return v >= 0.f ? v : 0.2f * v; }
__device__ __forceinline__ float bflo(unsigned u){ return __uint_as_float(u << 16); }
__device__ __forceinline__ float bfhi(unsigned u){ return __uint_as_float(u & 0xffff0000u); }

// async global->LDS, 4 bytes/lane: lane l writes lds_base + l*4
__device__ __forceinline__ void gld_lds4(const float* g, float* l){
    __builtin_amdgcn_global_load_lds(
        (const __attribute__((address_space(1))) unsigned int*)g,
        (__attribute__((address_space(3))) unsigned int*)l, 4, 0, 0);
}

// ---------------- cooperative CSR build (+ W1 prep) in ONE dispatch ----------------
// phases: {deg zero, w1 transpose/split} | hist | chunk sums | scan chunks | row_off/cursor | scatter
__global__ __launch_bounds__(256) void k_csr(const float* __restrict__ W1,
    __bf16* __restrict__ w1h, __bf16* __restrict__ w1l,
    const int* __restrict__ src, const int* __restrict__ dst,
    int* __restrict__ deg, int* __restrict__ bsum,
    int* __restrict__ row_off, int* __restrict__ cursor,
    int* __restrict__ csr, int E)
{
    cg::grid_group grid = cg::this_grid();
    const int gsize = gridDim.x * 256;
    const int gtid  = blockIdx.x * 256 + threadIdx.x;
    __shared__ int s[256];

    // phase 0: zero deg + W1 transpose/split (independent streams of work)
    for (int i = gtid; i < NN; i += gsize) deg[i] = 0;
    for (int i = gtid; i < 64 * KPAD; i += gsize){
        int c = i / KPAD, k = i - c * KPAD;
        float v = (k < FIN) ? W1[(size_t)k * 64 + c] : 0.f;
        __bf16 hi = (__bf16)v;
        w1h[(size_t)c * KPAD + k] = hi;
        w1l[(size_t)c * KPAD + k] = (__bf16)(v - (float)hi);
    }
    grid.sync();

    // phase 1: degree histogram
    for (int i = gtid; i < E; i += gsize) atomicAdd(&deg[dst[i]], 1);
    grid.sync();

    // phase 2a: per-chunk sums (NB_SCAN chunks of 256)
    for (int c = blockIdx.x; c < NB_SCAN; c += gridDim.x){
        int i = c * 256 + threadIdx.x;
        s[threadIdx.x] = (i < NN) ? deg[i] : 0;
        __syncthreads();
        for (int off = 128; off > 0; off >>= 1){
            if (threadIdx.x < off) s[threadIdx.x] += s[threadIdx.x + off];
            __syncthreads();
        }
        if (threadIdx.x == 0) bsum[c] = s[0];
        __syncthreads();
    }
    grid.sync();

    // phase 2b: block 0 turns bsum into EXCLUSIVE chunk offsets
    if (blockIdx.x == 0){
        int t = threadIdx.x;
        int v = (t < NB_SCAN) ? bsum[t] : 0;
        s[t] = v;
        __syncthreads();
        for (int off = 1; off < 256; off <<= 1){
            int x_ = s[t];
            int add = (t >= off) ? s[t - off] : 0;
            __syncthreads();
            s[t] = x_ + add;
            __syncthreads();
        }
        if (t < NB_SCAN) bsum[t] = s[t] - v;     // exclusive
    }
    grid.sync();

    // phase 2c: per-chunk inclusive scan -> row_off + cursor
    for (int c = blockIdx.x; c < NB_SCAN; c += gridDim.x){
        int t = threadIdx.x;
        int i = c * 256 + t;
        int d = (i < NN) ? deg[i] : 0;
        s[t] = d;
        __syncthreads();
        for (int off = 1; off < 256; off <<= 1){
            int v = s[t];
            int add = (t >= off) ? s[t - off] : 0;
            __syncthreads();
            s[t] = v + add;
            __syncthreads();
        }
        int excl = s[t] - d + bsum[c];
        if (i < NN){
            row_off[i] = excl; cursor[i] = excl;
            if (i == NN - 1) row_off[NN] = excl + d;
        }
        __syncthreads();
    }
    grid.sync();

    // phase 3: scatter (cursor atomics; rank array eliminated)
    for (int i = gtid; i < E; i += gsize){
        int dd = dst[i];
        int pos = atomicAdd(&cursor[dd], 1);
        csr[pos] = src[i];
    }
}

// ---------------- GEMM1: H = x @ W1 -> Hb[N][64] bf16 (128B rows) ----------------
__global__ __launch_bounds__(256, 4) void k_gemm1(const float* __restrict__ x,
    const __bf16* __restrict__ w1h, const __bf16* __restrict__ w1l,
    __bf16* __restrict__ Hb)
{
    __shared__ float  As[64 * 68];           // 17.4 KB f32 staging (stride 68)
    __shared__ __bf16 AH[64 * 72];           // 9.2 KB hi plane (stride 72)
    __shared__ __bf16 AL[64 * 72];           // 9.2 KB lo plane
    const int tid  = threadIdx.x;
    const int w    = tid >> 6;
    const int lane = tid & 63;
    const int lr   = lane & 15;
    const int lk   = lane >> 4;
    const int rbase = blockIdx.x * 64;
    const int cr = tid >> 2;
    const int cg_ = (tid & 3) * 16;

    unsigned rowoff[16];
    #pragma unroll
    for (int i = 0; i < 16; ++i){
        int rg = rbase + w * 16 + i; if (rg >= NN) rg = NN - 1;
        rowoff[i] = (unsigned)rg * (unsigned)FIN + (unsigned)lane;
    }

    const __bf16* bh_p = w1h + (size_t)(w * 16 + lr) * KPAD + lk * 8;
    const __bf16* bl_p = w1l + (size_t)(w * 16 + lr) * KPAD + lk * 8;

    f32x4 acc[4] = {{0,0,0,0},{0,0,0,0},{0,0,0,0},{0,0,0,0}};

    #pragma unroll
    for (int i = 0; i < 16; ++i)
        gld_lds4(x + rowoff[i], &As[(w * 16 + i) * 68]);
    __syncthreads();

    for (int kb = 0; kb < 22; ++kb){
        {   // one-time convert As -> AH/AL
            const float* rp = &As[cr * 68 + cg_];
            f32x4 v[4];
            #pragma unroll
            for (int j = 0; j < 4; ++j) v[j] = *(const f32x4*)(rp + j * 4);
            bf16x8 hv0, hv1, lv0, lv1;
            #pragma unroll
            for (int j = 0; j < 2; ++j){
                #pragma unroll
                for (int e = 0; e < 4; ++e){
                    float a0 = v[2 * j][e], a1 = v[2 * j + 1][e];
                    __bf16 h0 = (__bf16)a0, h1 = (__bf16)a1;
                    if (j == 0){ hv0[e] = h0; hv0[e + 4] = h1;
                                 lv0[e] = (__bf16)(a0 - (float)h0);
                                 lv0[e + 4] = (__bf16)(a1 - (float)h1); }
                    else       { hv1[e] = h0; hv1[e + 4] = h1;
                                 lv1[e] = (__bf16)(a0 - (float)h0);
                                 lv1[e + 4] = (__bf16)(a1 - (float)h1); }
                }
            }
            *(bf16x8*)&AH[cr * 72 + cg_]     = hv0;
            *(bf16x8*)&AH[cr * 72 + cg_ + 8] = hv1;
            *(bf16x8*)&AL[cr * 72 + cg_]     = lv0;
            *(bf16x8*)&AL[cr * 72 + cg_ + 8] = lv1;
        }
        __syncthreads();

        if (kb < 21){
            const float* gsrc = x + (kb + 1) * 64;
            #pragma unroll
            for (int i = 0; i < 16; ++i)
                gld_lds4(gsrc + rowoff[i], &As[(w * 16 + i) * 68]);
        }

        const int kA = kb * 64;
        bf16x8 bh0 = *(const bf16x8*)(bh_p + kA);
        bf16x8 bl0 = *(const bf16x8*)(bl_p + kA);
        bf16x8 bh1 = *(const bf16x8*)(bh_p + kA + 32);
        bf16x8 bl1 = *(const bf16x8*)(bl_p + kA + 32);
        #pragma unroll
        for (int ks = 0; ks < 2; ++ks){
            bf16x8 bh = ks ? bh1 : bh0;
            bf16x8 bl = ks ? bl1 : bl0;
            #pragma unroll
            for (int t = 0; t < 4; ++t){
                const int ao = (t * 16 + lr) * 72 + ks * 32 + lk * 8;
                bf16x8 ah = *(const bf16x8*)&AH[ao];
                bf16x8 al = *(const bf16x8*)&AL[ao];
                acc[t] = __builtin_amdgcn_mfma_f32_16x16x32_bf16(ah, bh, acc[t], 0, 0, 0);
                acc[t] = __builtin_amdgcn_mfma_f32_16x16x32_bf16(al, bh, acc[t], 0, 0, 0);
                acc[t] = __builtin_amdgcn_mfma_f32_16x16x32_bf16(ah, bl, acc[t], 0, 0, 0);
            }
        }
        __syncthreads();
    }

    // peeled masked tail: k 1408..1439 (valid < 1433)
    {
        bf16x8 bh = *(const bf16x8*)(bh_p + 1408);
        bf16x8 bl = *(const bf16x8*)(bl_p + 1408);
        #pragma unroll
        for (int t = 0; t < 4; ++t){
            int rg = rbase + t * 16 + lr; if (rg >= NN) rg = NN - 1;
            const float* xr = x + (size_t)rg * FIN;
            bf16x8 ah, al;
            #pragma unroll
            for (int e = 0; e < 8; ++e){
                int k = 1408 + lk * 8 + e;
                float v = (k < FIN) ? xr[k] : 0.f;
                __bf16 h = (__bf16)v;
                ah[e] = h; al[e] = (__bf16)(v - (float)h);
            }
            acc[t] = __builtin_amdgcn_mfma_f32_16x16x32_bf16(ah, bh, acc[t], 0, 0, 0);
            acc[t] = __builtin_amdgcn_mfma_f32_16x16x32_bf16(al, bh, acc[t], 0, 0, 0);
            acc[t] = __builtin_amdgcn_mfma_f32_16x16x32_bf16(ah, bl, acc[t], 0, 0, 0);
        }
    }

    // epilogue: bf16 stores to Hb[N][64]
    const int col = w * 16 + lr;
    #pragma unroll
    for (int t = 0; t < 4; ++t){
        #pragma unroll
        for (int r = 0; r < 4; ++r){
            int row = rbase + t * 16 + lk * 4 + r;
            if (row < NN) Hb[(size_t)row * 64 + col] = (__bf16)acc[t][r];
        }
    }
}

// ---------------- layer-1 edge pass: alpha computed IN-REGISTER from H ----------------
// wave = 1 dst node; lane l = (edge slot e8 = l>>3) x (head c8 = l&7 -> 8 ch, uint4).
// 2 VMEM per 8-edge batch. Output x2b row stored bf16.
__global__ __launch_bounds__(256, 8) void k_layer1(const float* __restrict__ a_s,
    const float* __restrict__ a_d,
    const __bf16* __restrict__ Hb, const int* __restrict__ row_off, const int* __restrict__ csr,
    const float* __restrict__ b1, __bf16* __restrict__ x2b)
{
    const int d  = blockIdx.x * 4 + (threadIdx.x >> 6);
    const int l  = threadIdx.x & 63;
    const int e8 = l >> 3;           // edge slot (0..7)
    const int c8 = l & 7;            // head
    const int c0 = c8 * 8;

    float asw[8], adw[8];
    #pragma unroll
    for (int j = 0; j < 8; ++j){ asw[j] = a_s[c0 + j]; adw[j] = a_d[c0 + j]; }

    // self row: adv (dst alpha) + self-loop contribution
    float den = 0.f;
    float a[8] = {0.f,0.f,0.f,0.f,0.f,0.f,0.f,0.f};
    float adv;
    {
        uint4 hs = *(const uint4*)&Hb[(size_t)d * 64 + c0];
        float hv[8] = { bflo(hs.x), bfhi(hs.x), bflo(hs.y), bfhi(hs.y),
                        bflo(hs.z), bfhi(hs.z), bflo(hs.w), bfhi(hs.w) };
        float ad_ = 0.f, as_ = 0.f;
        #pragma unroll
        for (int j = 0; j < 8; ++j){
            ad_ = fmaf(hv[j], adw[j], ad_);
            as_ = fmaf(hv[j], asw[j], as_);
        }
        adv = ad_;
        if (e8 == 0){
            float p0 = __expf(leaky02(as_ + adv) - 20.f);   // fixed-offset softmax
            den = p0;
            #pragma unroll
            for (int j = 0; j < 8; ++j) a[j] = p0 * hv[j];
        }
    }

    const int beg = row_off[d], end = row_off[d + 1];
    const int nb = (end - beg + 7) >> 3;     // 8-edge batches
    int csrv = 0;
    if (nb > 0){
        int idx = beg + c8; if (idx >= end) idx = end - 1;
        csrv = __builtin_nontemporal_load(csr + idx);
    }
    for (int b = 0; b < nb; ++b){
        const int base = beg + b * 8;
        int ncsr = 0;
        if (b + 1 < nb){
            int idx = base + 8 + c8; if (idx >= end) idx = end - 1;
            ncsr = __builtin_nontemporal_load(csr + idx);
        }
        int s = __shfl(csrv, e8, 8);
        const bool val = (base + e8) < end;
        uint4 hw = make_uint4(0u,0u,0u,0u);
        if (val) hw = *(const uint4*)&Hb[(size_t)s * 64 + c0];
        if (val){
            float g[8] = { bflo(hw.x), bfhi(hw.x), bflo(hw.y), bfhi(hw.y),
                           bflo(hw.z), bfhi(hw.z), bflo(hw.w), bfhi(hw.w) };
            float av = 0.f;
            #pragma unroll
            for (int j = 0; j < 8; ++j) av = fmaf(g[j], asw[j], av);
            float p = __expf(leaky02(av + adv) - 20.f);
            den += p;
            #pragma unroll
            for (int j = 0; j < 8; ++j) a[j] = fmaf(p, g[j], a[j]);
        }
        csrv = ncsr;
    }

    // reduce over edge slots (lane bits 3..5)
    #pragma unroll
    for (int m = 8; m <= 32; m <<= 1){
        den += __shfl_xor(den, m, 64);
        #pragma unroll
        for (int j = 0; j < 8; ++j) a[j] += __shfl_xor(a[j], m, 64);
    }

    if (e8 == 0){
        float inv = 1.f / den;
        __bf16 ov[8];
        #pragma unroll
        for (int j = 0; j < 8; ++j){
            float v = a[j] * inv + b1[c0 + j];
            ov[j] = (__bf16)((v > 0.f) ? v : (__expf(v) - 1.f));   // ELU fused
        }
        *(uint4*)&x2b[(size_t)d * 64 + c0] = *(uint4*)ov;
    }
}

// ---------------- GEMM2 + attention logits, layer 2 ----------------
// x2b read as 8 x uint4 per node. h2b[n][8] bf16: [0..6]=h2, [7]=as2 (16B record)
__global__ __launch_bounds__(256) void k_gemm2(const __bf16* __restrict__ x2b, const float* __restrict__ W2,
    const float* __restrict__ aw_in, const float* __restrict__ dw_in,
    __bf16* __restrict__ h2b, float* __restrict__ ad2)
{
    __shared__ float w2s[448];
    __shared__ float aw[7], dw[7];
    int tid = threadIdx.x;
    for (int i = tid; i < 448; i += 256) w2s[i] = W2[i];
    if (tid < 7){ aw[tid] = aw_in[tid]; dw[tid] = dw_in[tid]; }
    __syncthreads();
    int n = blockIdx.x * 256 + tid;
    if (n >= NN) return;
    const uint4* xp = (const uint4*)(x2b + (size_t)n * 64);
    float acc[7] = {0.f,0.f,0.f,0.f,0.f,0.f,0.f};
    #pragma unroll
    for (int q = 0; q < 8; ++q){
        uint4 v = xp[q];
        float vv[8] = { bflo(v.x), bfhi(v.x), bflo(v.y), bfhi(v.y),
                        bflo(v.z), bfhi(v.z), bflo(v.w), bfhi(v.w) };
        #pragma unroll
        for (int u = 0; u < 8; ++u){
            int k = q * 8 + u;
            #pragma unroll
            for (int c = 0; c < 7; ++c) acc[c] = fmaf(vv[u], w2s[k * 7 + c], acc[c]);
        }
    }
    float s = 0.f, d = 0.f;
    #pragma unroll
    for (int c = 0; c < 7; ++c){ s = fmaf(acc[c], aw[c], s); d = fmaf(acc[c], dw[c], d); }
    __bf16 rec[8];
    #pragma unroll
    for (int c = 0; c < 7; ++c) rec[c] = (__bf16)acc[c];
    rec[7] = (__bf16)s;                         // as2 packed in slot 7
    *(uint4*)&h2b[(size_t)n * 8] = *(uint4*)rec;
    ad2[n] = d;
}

// ---------------- layer-2 edge pass + bias + log_softmax ----------------
// 8 lanes/node, lane = edge slot; one uint4 load = full record (h2[0..6] + as2).
__global__ __launch_bounds__(256, 8) void k_layer2(const float* __restrict__ ad2,
    const __bf16* __restrict__ h2b, const int* __restrict__ row_off, const int* __restrict__ csr,
    const float* __restrict__ b2, float* __restrict__ out)
{
    int tid  = threadIdx.x;
    int node = blockIdx.x * 32 + (tid >> 3);
    int sl   = tid & 7;                          // edge slot within node group
    if (node >= NN) return;
    float adv = ad2[node];

    float den = 0.f;
    float a[7] = {0.f,0.f,0.f,0.f,0.f,0.f,0.f};
    {   // self loop (once, slot 0)
        uint4 hs = *(const uint4*)&h2b[(size_t)node * 8];
        float h[8] = { bflo(hs.x), bfhi(hs.x), bflo(hs.y), bfhi(hs.y),
                       bflo(hs.z), bfhi(hs.z), bflo(hs.w), bfhi(hs.w) };
        if (sl == 0){
            float p0 = __expf(leaky02(h[7] + adv) - 20.f);
            den = p0;
            #pragma unroll
            for (int c = 0; c < 7; ++c) a[c] = p0 * h[c];
        }
    }

    const int beg = row_off[node], end = row_off[node + 1];
    const int nb = (end - beg + 7) >> 3;
    int csrv = 0;
    if (nb > 0){
        int idx = beg + sl; if (idx >= end) idx = end - 1;
        csrv = __builtin_nontemporal_load(csr + idx);
    }
    for (int b = 0; b < nb; ++b){
        const int base = beg + b * 8;
        int ncsr = 0;
        if (b + 1 < nb){
            int idx = base + 8 + sl; if (idx >= end) idx = end - 1;
            ncsr = __builtin_nontemporal_load(csr + idx);
        }
        const bool val = (base + sl) < end;
        uint4 hw = make_uint4(0u,0u,0u,0u);
        if (val) hw = *(const uint4*)&h2b[(size_t)csrv * 8];
        if (val){
            float g[8] = { bflo(hw.x), bfhi(hw.x), bflo(hw.y), bfhi(hw.y),
                           bflo(hw.z), bfhi(hw.z), bflo(hw.w), bfhi(hw.w) };
            float p = __expf(leaky02(g[7] + adv) - 20.f);
            den += p;
            #pragma unroll
            for (int c = 0; c < 7; ++c) a[c] = fmaf(p, g[c], a[c]);
        }
        csrv = ncsr;
    }

    // reduce within the node's 8 lanes (lane bits 0..2)
    #pragma unroll
    for (int m = 1; m <= 4; m <<= 1){
        den += __shfl_xor(den, m, 64);
        #pragma unroll
        for (int c = 0; c < 7; ++c) a[c] += __shfl_xor(a[c], m, 64);
    }

    if (sl == 0){
        float inv = 1.f / den;
        float v[7];
        #pragma unroll
        for (int c = 0; c < 7; ++c) v[c] = a[c] * inv + b2[c];
        float mx = v[0];
        #pragma unroll
        for (int c = 1; c < 7; ++c) mx = fmaxf(mx, v[c]);
        float s7 = 0.f;
        #pragma unroll
        for (int c = 0; c < 7; ++c) s7 += __expf(v[c] - mx);
        float lg = mx + __logf(s7);
        float* op = &out[(size_t)node * 7];
        #pragma unroll
        for (int c = 0; c < 7; ++c) op[c] = v[c] - lg;
    }
}

// ---------------- launcher ----------------
extern "C" void kernel_launch(void* const* d_in, const int* in_sizes, int n_in,
                              void* d_out, int out_size, void* d_ws, size_t ws_size,
                              hipStream_t stream)
{
    (void)n_in; (void)out_size; (void)ws_size;
    const float* x      = (const float*)d_in[0];
    const int*   ei     = (const int*)d_in[1];
    int          E      = in_sizes[1] / 2;
    const float* W1     = (const float*)d_in[2];
    const float* asrc1  = (const float*)d_in[3];
    const float* adst1  = (const float*)d_in[4];
    const float* b1     = (const float*)d_in[5];
    const float* W2     = (const float*)d_in[6];
    const float* asrc2  = (const float*)d_in[7];
    const float* adst2  = (const float*)d_in[8];
    const float* b2     = (const float*)d_in[9];
    float* out = (float*)d_out;

    char* p = (char*)d_ws;
    auto alloc = [&](size_t bytes) -> void* {
        void* r = (void*)p;
        p += (bytes + 255) & ~(size_t)255;
        return r;
    };
    int*    deg     = (int*)alloc((size_t)NN * 4);
    int*    row_off = (int*)alloc((size_t)(NN + 1) * 4);
    int*    cursor  = (int*)alloc((size_t)NN * 4);
    int*    bsum    = (int*)alloc((size_t)NB_SCAN * 4);
    int*    csr     = (int*)alloc((size_t)E * 4);
    __bf16* w1h     = (__bf16*)alloc((size_t)64 * KPAD * 2);
    __bf16* w1l     = (__bf16*)alloc((size_t)64 * KPAD * 2);
    __bf16* Hb      = (__bf16*)alloc((size_t)NN * 64 * 2);   // 128B rows
    __bf16* x2b     = (__bf16*)alloc((size_t)NN * 64 * 2);   // bf16 x2
    __bf16* h2b     = (__bf16*)alloc((size_t)NN * 8 * 2);    // 16B records
    float*  ad2     = (float*)alloc((size_t)NN * 4);

    const int* src = ei;
    const int* dst = ei + E;

    {   // cooperative CSR build (+prep) — one dispatch replaces five
        void* args[] = { (void*)&W1, (void*)&w1h, (void*)&w1l,
                         (void*)&src, (void*)&dst, (void*)&deg, (void*)&bsum,
                         (void*)&row_off, (void*)&cursor, (void*)&csr, (void*)&E };
        hipLaunchCooperativeKernel((const void*)k_csr, dim3(CSRG), dim3(256),
                                   args, 0, stream);
    }
    k_gemm1  <<<(NN + 63) / 64, 256, 0, stream>>>(x, w1h, w1l, Hb);
    k_layer1 <<<L1B, 256, 0, stream>>>(asrc1, adst1, Hb, row_off, csr, b1, x2b);
    k_gemm2  <<<(NN + 255) / 256, 256, 0, stream>>>(x2b, W2, asrc2, adst2, h2b, ad2);
    k_layer2 <<<(NN + 31) / 32, 256, 0, stream>>>(ad2, h2b, row_off, csr, b2, out);
}

// Round 19
// 282.515 us; speedup vs baseline: 3.1786x; 3.1786x over previous
//
#include <hip/hip_runtime.h>
#include <hip/hip_bf16.h>

static constexpr int NN      = 50000;
static constexpr int FIN     = 1433;
static constexpr int KPAD    = 1440;            // 45 * 32
static constexpr int NB_SCAN = (NN + 255) / 256; // 196
static constexpr int L1B     = NN / 4;           // 12500 blocks, 1 node/wave

typedef __bf16 bf16x8 __attribute__((ext_vector_type(8)));
typedef float  f32x4  __attribute__((ext_vector_type(4)));

__device__ __forceinline__ float leaky02(float v){ return v >= 0.f ? v : 0.2f * v; }
__device__ __forceinline__ float bflo(unsigned u){ return __uint_as_float(u << 16); }
__device__ __forceinline__ float bfhi(unsigned u){ return __uint_as_float(u & 0xffff0000u); }

// async global->LDS, 4 bytes/lane: lane l writes lds_base + l*4
__device__ __forceinline__ void gld_lds4(const float* g, float* l){
    __builtin_amdgcn_global_load_lds(
        (const __attribute__((address_space(1))) unsigned int*)g,
        (__attribute__((address_space(3))) unsigned int*)l, 4, 0, 0);
}

// ---------------- prep: W1 transpose/split + deg zero, one dispatch ----------------
__global__ __launch_bounds__(256) void k_prep(const float* __restrict__ W1,
                                              __bf16* __restrict__ w1h, __bf16* __restrict__ w1l,
                                              int* __restrict__ deg){
    int bid = blockIdx.x;
    if (bid < 64){
        int c = bid;                          // output column
        for (int k = threadIdx.x; k < KPAD; k += 256){
            float v = (k < FIN) ? W1[(size_t)k * 64 + c] : 0.f;
            __bf16 hi = (__bf16)v;
            w1h[(size_t)c * KPAD + k] = hi;
            w1l[(size_t)c * KPAD + k] = (__bf16)(v - (float)hi);
        }
    } else {
        int i = (bid - 64) * 256 + threadIdx.x;
        if (i < NN) deg[i] = 0;
    }
}

// ---------------- CSR build ----------------
// rank packs (r<<16)|d : d < 50000 < 2^16, degree < 2^16 for this graph.
__global__ __launch_bounds__(256) void k_rank(const int* __restrict__ dst, int* __restrict__ deg,
                                              int* __restrict__ rank, int E){
    int base = blockIdx.x * 1024 + threadIdx.x;
    int d[4]; bool v[4];
    #pragma unroll
    for (int i = 0; i < 4; ++i){
        int e = base + i * 256;
        v[i] = e < E;
        d[i] = v[i] ? dst[e] : 0;
    }
    int r[4];
    #pragma unroll
    for (int i = 0; i < 4; ++i)
        if (v[i]) r[i] = atomicAdd(&deg[d[i]], 1);
    #pragma unroll
    for (int i = 0; i < 4; ++i)
        if (v[i]) rank[base + i * 256] = (r[i] << 16) | d[i];
}

__global__ __launch_bounds__(256) void k_scan1(const int* __restrict__ deg, int* __restrict__ bsum){
    __shared__ int red[256];
    int i = blockIdx.x * 256 + threadIdx.x;
    red[threadIdx.x] = (i < NN) ? deg[i] : 0;
    __syncthreads();
    for (int off = 128; off > 0; off >>= 1){
        if (threadIdx.x < off) red[threadIdx.x] += red[threadIdx.x + off];
        __syncthreads();
    }
    if (threadIdx.x == 0) bsum[blockIdx.x] = red[0];
}

// scan3 with scan2 folded in
__global__ __launch_bounds__(256) void k_scan3(const int* __restrict__ deg, const int* __restrict__ bsum,
                                               int* __restrict__ row_off){
    __shared__ int s[256];
    int t = threadIdx.x;
    int i = blockIdx.x * 256 + t;
    s[t] = (t < blockIdx.x) ? bsum[t] : 0;
    __syncthreads();
    for (int off = 128; off > 0; off >>= 1){
        if (t < off) s[t] += s[t + off];
        __syncthreads();
    }
    int bofs = s[0];
    __syncthreads();
    int d = (i < NN) ? deg[i] : 0;
    s[t] = d;
    __syncthreads();
    for (int off = 1; off < 256; off <<= 1){
        int v = s[t];
        int a = (t >= off) ? s[t - off] : 0;
        __syncthreads();
        s[t] = v + a;
        __syncthreads();
    }
    int excl = s[t] - d + bofs;
    if (i < NN){
        row_off[i] = excl;
        if (i == NN - 1) row_off[NN] = excl + d;
    }
}

// atomic-free scatter; dst recovered from packed rank (one fewer stream read)
__global__ __launch_bounds__(256) void k_scatter(const int* __restrict__ src,
                                                 const int* __restrict__ rank, const int* __restrict__ row_off,
                                                 int* __restrict__ csr, int E){
    int base = blockIdx.x * 1024 + threadIdx.x;
    int pk[4], sv[4]; bool v[4];
    #pragma unroll
    for (int i = 0; i < 4; ++i){
        int e = base + i * 256;
        v[i] = e < E;
        if (v[i]){ pk[i] = rank[e]; sv[i] = src[e]; }
    }
    int ro[4];
    #pragma unroll
    for (int i = 0; i < 4; ++i)
        if (v[i]) ro[i] = row_off[pk[i] & 0xffff];
    #pragma unroll
    for (int i = 0; i < 4; ++i)
        if (v[i]) csr[ro[i] + (pk[i] >> 16)] = sv[i];
}

// ---------------- GEMM1: H = x @ W1 -> Hb[N][64] bf16 (128B rows) ----------------
__global__ __launch_bounds__(256, 4) void k_gemm1(const float* __restrict__ x,
    const __bf16* __restrict__ w1h, const __bf16* __restrict__ w1l,
    __bf16* __restrict__ Hb)
{
    __shared__ float  As[64 * 68];           // 17.4 KB f32 staging (stride 68)
    __shared__ __bf16 AH[64 * 72];           // 9.2 KB hi plane (stride 72)
    __shared__ __bf16 AL[64 * 72];           // 9.2 KB lo plane
    const int tid  = threadIdx.x;
    const int w    = tid >> 6;
    const int lane = tid & 63;
    const int lr   = lane & 15;
    const int lk   = lane >> 4;
    const int rbase = blockIdx.x * 64;
    const int cr = tid >> 2;
    const int cg = (tid & 3) * 16;

    unsigned rowoff[16];
    #pragma unroll
    for (int i = 0; i < 16; ++i){
        int rg = rbase + w * 16 + i; if (rg >= NN) rg = NN - 1;
        rowoff[i] = (unsigned)rg * (unsigned)FIN + (unsigned)lane;
    }

    const __bf16* bh_p = w1h + (size_t)(w * 16 + lr) * KPAD + lk * 8;
    const __bf16* bl_p = w1l + (size_t)(w * 16 + lr) * KPAD + lk * 8;

    f32x4 acc[4] = {{0,0,0,0},{0,0,0,0},{0,0,0,0},{0,0,0,0}};

    #pragma unroll
    for (int i = 0; i < 16; ++i)
        gld_lds4(x + rowoff[i], &As[(w * 16 + i) * 68]);
    __syncthreads();

    for (int kb = 0; kb < 22; ++kb){
        {   // one-time convert As -> AH/AL
            const float* rp = &As[cr * 68 + cg];
            f32x4 v[4];
            #pragma unroll
            for (int j = 0; j < 4; ++j) v[j] = *(const f32x4*)(rp + j * 4);
            bf16x8 hv0, hv1, lv0, lv1;
            #pragma unroll
            for (int j = 0; j < 2; ++j){
                #pragma unroll
                for (int e = 0; e < 4; ++e){
                    float a0 = v[2 * j][e], a1 = v[2 * j + 1][e];
                    __bf16 h0 = (__bf16)a0, h1 = (__bf16)a1;
                    if (j == 0){ hv0[e] = h0; hv0[e + 4] = h1;
                                 lv0[e] = (__bf16)(a0 - (float)h0);
                                 lv0[e + 4] = (__bf16)(a1 - (float)h1); }
                    else       { hv1[e] = h0; hv1[e + 4] = h1;
                                 lv1[e] = (__bf16)(a0 - (float)h0);
                                 lv1[e + 4] = (__bf16)(a1 - (float)h1); }
                }
            }
            *(bf16x8*)&AH[cr * 72 + cg]     = hv0;
            *(bf16x8*)&AH[cr * 72 + cg + 8] = hv1;
            *(bf16x8*)&AL[cr * 72 + cg]     = lv0;
            *(bf16x8*)&AL[cr * 72 + cg + 8] = lv1;
        }
        __syncthreads();

        if (kb < 21){
            const float* gsrc = x + (kb + 1) * 64;
            #pragma unroll
            for (int i = 0; i < 16; ++i)
                gld_lds4(gsrc + rowoff[i], &As[(w * 16 + i) * 68]);
        }

        const int kA = kb * 64;
        bf16x8 bh0 = *(const bf16x8*)(bh_p + kA);
        bf16x8 bl0 = *(const bf16x8*)(bl_p + kA);
        bf16x8 bh1 = *(const bf16x8*)(bh_p + kA + 32);
        bf16x8 bl1 = *(const bf16x8*)(bl_p + kA + 32);
        #pragma unroll
        for (int ks = 0; ks < 2; ++ks){
            bf16x8 bh = ks ? bh1 : bh0;
            bf16x8 bl = ks ? bl1 : bl0;
            #pragma unroll
            for (int t = 0; t < 4; ++t){
                const int ao = (t * 16 + lr) * 72 + ks * 32 + lk * 8;
                bf16x8 ah = *(const bf16x8*)&AH[ao];
                bf16x8 al = *(const bf16x8*)&AL[ao];
                acc[t] = __builtin_amdgcn_mfma_f32_16x16x32_bf16(ah, bh, acc[t], 0, 0, 0);
                acc[t] = __builtin_amdgcn_mfma_f32_16x16x32_bf16(al, bh, acc[t], 0, 0, 0);
                acc[t] = __builtin_amdgcn_mfma_f32_16x16x32_bf16(ah, bl, acc[t], 0, 0, 0);
            }
        }
        __syncthreads();
    }

    // peeled masked tail: k 1408..1439 (valid < 1433)
    {
        bf16x8 bh = *(const bf16x8*)(bh_p + 1408);
        bf16x8 bl = *(const bf16x8*)(bl_p + 1408);
        #pragma unroll
        for (int t = 0; t < 4; ++t){
            int rg = rbase + t * 16 + lr; if (rg >= NN) rg = NN - 1;
            const float* xr = x + (size_t)rg * FIN;
            bf16x8 ah, al;
            #pragma unroll
            for (int e = 0; e < 8; ++e){
                int k = 1408 + lk * 8 + e;
                float v = (k < FIN) ? xr[k] : 0.f;
                __bf16 h = (__bf16)v;
                ah[e] = h; al[e] = (__bf16)(v - (float)h);
            }
            acc[t] = __builtin_amdgcn_mfma_f32_16x16x32_bf16(ah, bh, acc[t], 0, 0, 0);
            acc[t] = __builtin_amdgcn_mfma_f32_16x16x32_bf16(al, bh, acc[t], 0, 0, 0);
            acc[t] = __builtin_amdgcn_mfma_f32_16x16x32_bf16(ah, bl, acc[t], 0, 0, 0);
        }
    }

    // epilogue: bf16 stores to Hb[N][64]
    const int col = w * 16 + lr;
    #pragma unroll
    for (int t = 0; t < 4; ++t){
        #pragma unroll
        for (int r = 0; r < 4; ++r){
            int row = rbase + t * 16 + lk * 4 + r;
            if (row < NN) Hb[(size_t)row * 64 + col] = (__bf16)acc[t][r];
        }
    }
}

// ---------------- layer-1 edge pass: alpha computed IN-REGISTER from H ----------------
// wave = 1 dst node; lane l = (edge slot e8 = l>>3) x (head c8 = l&7 -> 8 ch, uint4).
// 2 VMEM per 8-edge batch. a_s/a_d/b1 loaded as float4 (4 VMEM instead of 16).
__global__ __launch_bounds__(256, 8) void k_layer1(const float* __restrict__ a_s,
    const float* __restrict__ a_d,
    const __bf16* __restrict__ Hb, const int* __restrict__ row_off, const int* __restrict__ csr,
    const float* __restrict__ b1, __bf16* __restrict__ x2b)
{
    const int d  = blockIdx.x * 4 + (threadIdx.x >> 6);
    const int l  = threadIdx.x & 63;
    const int e8 = l >> 3;           // edge slot (0..7)
    const int c8 = l & 7;            // head
    const int c0 = c8 * 8;

    float asw[8], adw[8];
    {
        float4 s0 = *(const float4*)(a_s + c0);
        float4 s1 = *(const float4*)(a_s + c0 + 4);
        float4 d0 = *(const float4*)(a_d + c0);
        float4 d1 = *(const float4*)(a_d + c0 + 4);
        asw[0]=s0.x; asw[1]=s0.y; asw[2]=s0.z; asw[3]=s0.w;
        asw[4]=s1.x; asw[5]=s1.y; asw[6]=s1.z; asw[7]=s1.w;
        adw[0]=d0.x; adw[1]=d0.y; adw[2]=d0.z; adw[3]=d0.w;
        adw[4]=d1.x; adw[5]=d1.y; adw[6]=d1.z; adw[7]=d1.w;
    }

    // self row: adv (dst alpha) + self-loop contribution
    float den = 0.f;
    float a[8] = {0.f,0.f,0.f,0.f,0.f,0.f,0.f,0.f};
    float adv;
    {
        uint4 hs = *(const uint4*)&Hb[(size_t)d * 64 + c0];
        float hv[8] = { bflo(hs.x), bfhi(hs.x), bflo(hs.y), bfhi(hs.y),
                        bflo(hs.z), bfhi(hs.z), bflo(hs.w), bfhi(hs.w) };
        float ad_ = 0.f, as_ = 0.f;
        #pragma unroll
        for (int j = 0; j < 8; ++j){
            ad_ = fmaf(hv[j], adw[j], ad_);
            as_ = fmaf(hv[j], asw[j], as_);
        }
        adv = ad_;
        if (e8 == 0){
            float p0 = __expf(leaky02(as_ + adv) - 20.f);   // fixed-offset softmax
            den = p0;
            #pragma unroll
            for (int j = 0; j < 8; ++j) a[j] = p0 * hv[j];
        }
    }

    const int beg = row_off[d], end = row_off[d + 1];
    const int nb = (end - beg + 7) >> 3;     // 8-edge batches
    int csrv = 0;
    if (nb > 0){
        int idx = beg + c8; if (idx >= end) idx = end - 1;
        csrv = __builtin_nontemporal_load(csr + idx);
    }
    for (int b = 0; b < nb; ++b){
        const int base = beg + b * 8;
        int ncsr = 0;
        if (b + 1 < nb){
            int idx = base + 8 + c8; if (idx >= end) idx = end - 1;
            ncsr = __builtin_nontemporal_load(csr + idx);
        }
        int s = __shfl(csrv, e8, 8);
        const bool val = (base + e8) < end;
        uint4 hw = make_uint4(0u,0u,0u,0u);
        if (val) hw = *(const uint4*)&Hb[(size_t)s * 64 + c0];
        if (val){
            float g[8] = { bflo(hw.x), bfhi(hw.x), bflo(hw.y), bfhi(hw.y),
                           bflo(hw.z), bfhi(hw.z), bflo(hw.w), bfhi(hw.w) };
            float av = 0.f;
            #pragma unroll
            for (int j = 0; j < 8; ++j) av = fmaf(g[j], asw[j], av);
            float p = __expf(leaky02(av + adv) - 20.f);
            den += p;
            #pragma unroll
            for (int j = 0; j < 8; ++j) a[j] = fmaf(p, g[j], a[j]);
        }
        csrv = ncsr;
    }

    // reduce over edge slots (lane bits 3..5)
    #pragma unroll
    for (int m = 8; m <= 32; m <<= 1){
        den += __shfl_xor(den, m, 64);
        #pragma unroll
        for (int j = 0; j < 8; ++j) a[j] += __shfl_xor(a[j], m, 64);
    }

    if (e8 == 0){
        float4 b0 = *(const float4*)(b1 + c0);
        float4 b1v = *(const float4*)(b1 + c0 + 4);
        float bb[8] = { b0.x, b0.y, b0.z, b0.w, b1v.x, b1v.y, b1v.z, b1v.w };
        float inv = 1.f / den;
        __bf16 ov[8];
        #pragma unroll
        for (int j = 0; j < 8; ++j){
            float v = a[j] * inv + bb[j];
            ov[j] = (__bf16)((v > 0.f) ? v : (__expf(v) - 1.f));   // ELU fused
        }
        *(uint4*)&x2b[(size_t)d * 64 + c0] = *(uint4*)ov;
    }
}

// ---------------- GEMM2 + attention logits, layer 2 ----------------
// x2b read as 8 x uint4 per node. h2b[n][8] bf16: [0..6]=h2, [7]=as2 (16B record)
__global__ __launch_bounds__(256) void k_gemm2(const __bf16* __restrict__ x2b, const float* __restrict__ W2,
    const float* __restrict__ aw_in, const float* __restrict__ dw_in,
    __bf16* __restrict__ h2b, float* __restrict__ ad2)
{
    __shared__ float w2s[448];
    __shared__ float aw[7], dw[7];
    int tid = threadIdx.x;
    for (int i = tid; i < 448; i += 256) w2s[i] = W2[i];
    if (tid < 7){ aw[tid] = aw_in[tid]; dw[tid] = dw_in[tid]; }
    __syncthreads();
    int n = blockIdx.x * 256 + tid;
    if (n >= NN) return;
    const uint4* xp = (const uint4*)(x2b + (size_t)n * 64);
    float acc[7] = {0.f,0.f,0.f,0.f,0.f,0.f,0.f};
    #pragma unroll
    for (int q = 0; q < 8; ++q){
        uint4 v = xp[q];
        float vv[8] = { bflo(v.x), bfhi(v.x), bflo(v.y), bfhi(v.y),
                        bflo(v.z), bfhi(v.z), bflo(v.w), bfhi(v.w) };
        #pragma unroll
        for (int u = 0; u < 8; ++u){
            int k = q * 8 + u;
            #pragma unroll
            for (int c = 0; c < 7; ++c) acc[c] = fmaf(vv[u], w2s[k * 7 + c], acc[c]);
        }
    }
    float s = 0.f, d = 0.f;
    #pragma unroll
    for (int c = 0; c < 7; ++c){ s = fmaf(acc[c], aw[c], s); d = fmaf(acc[c], dw[c], d); }
    __bf16 rec[8];
    #pragma unroll
    for (int c = 0; c < 7; ++c) rec[c] = (__bf16)acc[c];
    rec[7] = (__bf16)s;                         // as2 packed in slot 7
    *(uint4*)&h2b[(size_t)n * 8] = *(uint4*)rec;
    ad2[n] = d;
}

// ---------------- layer-2 edge pass + bias + log_softmax ----------------
// 8 lanes/node, lane = edge slot; one uint4 load = full record (h2[0..6] + as2).
__global__ __launch_bounds__(256, 8) void k_layer2(const float* __restrict__ ad2,
    const __bf16* __restrict__ h2b, const int* __restrict__ row_off, const int* __restrict__ csr,
    const float* __restrict__ b2, float* __restrict__ out)
{
    int tid  = threadIdx.x;
    int node = blockIdx.x * 32 + (tid >> 3);
    int sl   = tid & 7;                          // edge slot within node group
    if (node >= NN) return;
    float adv = ad2[node];

    float den = 0.f;
    float a[7] = {0.f,0.f,0.f,0.f,0.f,0.f,0.f};
    {   // self loop (once, slot 0)
        uint4 hs = *(const uint4*)&h2b[(size_t)node * 8];
        float h[8] = { bflo(hs.x), bfhi(hs.x), bflo(hs.y), bfhi(hs.y),
                       bflo(hs.z), bfhi(hs.z), bflo(hs.w), bfhi(hs.w) };
        if (sl == 0){
            float p0 = __expf(leaky02(h[7] + adv) - 20.f);
            den = p0;
            #pragma unroll
            for (int c = 0; c < 7; ++c) a[c] = p0 * h[c];
        }
    }

    const int beg = row_off[node], end = row_off[node + 1];
    const int nb = (end - beg + 7) >> 3;
    int csrv = 0;
    if (nb > 0){
        int idx = beg + sl; if (idx >= end) idx = end - 1;
        csrv = __builtin_nontemporal_load(csr + idx);
    }
    for (int b = 0; b < nb; ++b){
        const int base = beg + b * 8;
        int ncsr = 0;
        if (b + 1 < nb){
            int idx = base + 8 + sl; if (idx >= end) idx = end - 1;
            ncsr = __builtin_nontemporal_load(csr + idx);
        }
        const bool val = (base + sl) < end;
        uint4 hw = make_uint4(0u,0u,0u,0u);
        if (val) hw = *(const uint4*)&h2b[(size_t)csrv * 8];
        if (val){
            float g[8] = { bflo(hw.x), bfhi(hw.x), bflo(hw.y), bfhi(hw.y),
                           bflo(hw.z), bfhi(hw.z), bflo(hw.w), bfhi(hw.w) };
            float p = __expf(leaky02(g[7] + adv) - 20.f);
            den += p;
            #pragma unroll
            for (int c = 0; c < 7; ++c) a[c] = fmaf(p, g[c], a[c]);
        }
        csrv = ncsr;
    }

    // reduce within the node's 8 lanes (lane bits 0..2)
    #pragma unroll
    for (int m = 1; m <= 4; m <<= 1){
        den += __shfl_xor(den, m, 64);
        #pragma unroll
        for (int c = 0; c < 7; ++c) a[c] += __shfl_xor(a[c], m, 64);
    }

    if (sl == 0){
        float inv = 1.f / den;
        float v[7];
        #pragma unroll
        for (int c = 0; c < 7; ++c) v[c] = a[c] * inv + b2[c];
        float mx = v[0];
        #pragma unroll
        for (int c = 1; c < 7; ++c) mx = fmaxf(mx, v[c]);
        float s7 = 0.f;
        #pragma unroll
        for (int c = 0; c < 7; ++c) s7 += __expf(v[c] - mx);
        float lg = mx + __logf(s7);
        float* op = &out[(size_t)node * 7];
        #pragma unroll
        for (int c = 0; c < 7; ++c) op[c] = v[c] - lg;
    }
}

// ---------------- launcher ----------------
extern "C" void kernel_launch(void* const* d_in, const int* in_sizes, int n_in,
                              void* d_out, int out_size, void* d_ws, size_t ws_size,
                              hipStream_t stream)
{
    (void)n_in; (void)out_size; (void)ws_size;
    const float* x      = (const float*)d_in[0];
    const int*   ei     = (const int*)d_in[1];
    const int    E      = in_sizes[1] / 2;
    const float* W1     = (const float*)d_in[2];
    const float* asrc1  = (const float*)d_in[3];
    const float* adst1  = (const float*)d_in[4];
    const float* b1     = (const float*)d_in[5];
    const float* W2     = (const float*)d_in[6];
    const float* asrc2  = (const float*)d_in[7];
    const float* adst2  = (const float*)d_in[8];
    const float* b2     = (const float*)d_in[9];
    float* out = (float*)d_out;

    char* p = (char*)d_ws;
    auto alloc = [&](size_t bytes) -> void* {
        void* r = (void*)p;
        p += (bytes + 255) & ~(size_t)255;
        return r;
    };
    int*    deg     = (int*)alloc((size_t)NN * 4);
    int*    row_off = (int*)alloc((size_t)(NN + 1) * 4);
    int*    rank    = (int*)alloc((size_t)E * 4);
    int*    bsum    = (int*)alloc((size_t)NB_SCAN * 4);
    int*    csr     = (int*)alloc((size_t)E * 4);
    __bf16* w1h     = (__bf16*)alloc((size_t)64 * KPAD * 2);
    __bf16* w1l     = (__bf16*)alloc((size_t)64 * KPAD * 2);
    __bf16* Hb      = (__bf16*)alloc((size_t)NN * 64 * 2);   // 128B rows
    __bf16* x2b     = (__bf16*)alloc((size_t)NN * 64 * 2);   // bf16 x2
    __bf16* h2b     = (__bf16*)alloc((size_t)NN * 8 * 2);    // 16B records
    float*  ad2     = (float*)alloc((size_t)NN * 4);

    const int* src = ei;
    const int* dst = ei + E;

    k_prep   <<<64 + NB_SCAN, 256, 0, stream>>>(W1, w1h, w1l, deg);
    k_rank   <<<(E + 1023) / 1024, 256, 0, stream>>>(dst, deg, rank, E);
    k_scan1  <<<NB_SCAN, 256, 0, stream>>>(deg, bsum);
    k_scan3  <<<NB_SCAN, 256, 0, stream>>>(deg, bsum, row_off);
    k_scatter<<<(E + 1023) / 1024, 256, 0, stream>>>(src, rank, row_off, csr, E);
    k_gemm1  <<<(NN + 63) / 64, 256, 0, stream>>>(x, w1h, w1l, Hb);
    k_layer1 <<<L1B, 256, 0, stream>>>(asrc1, adst1, Hb, row_off, csr, b1, x2b);
    k_gemm2  <<<(NN + 255) / 256, 256, 0, stream>>>(x2b, W2, asrc2, adst2, h2b, ad2);
    k_layer2 <<<(NN + 31) / 32, 256, 0, stream>>>(ad2, h2b, row_off, csr, b2, out);
}